// Round 3
// baseline (2284.615 us; speedup 1.0000x reference)
//
#include <hip/hip_runtime.h>

#define N_NODES 100000
#define N_EDGES 1600000
#define N_GRAPHS 1000
#define SCAN_B 1024
#define SCAN_NB ((N_NODES + SCAN_B - 1) / SCAN_B)   // 98

#define HSTR 68   // LDS row stride (floats) for h tile  (16B-aligned rows, swizzle-friendly)
#define WSTR 68   // LDS row stride (floats) for W^T tile

// ---------- CSR build: histogram of dst + per-edge rank ----------
// rank r[e] = position of edge e within its dst segment (any order is fine:
// aggregation is a commutative sum), so the later bucket pass needs no atomics.
__global__ __launch_bounds__(256) void hist_kernel(
    const int* __restrict__ dst, int* __restrict__ deg, int* __restrict__ r)
{
    int e = blockIdx.x * 256 + threadIdx.x;
    if (e < N_EDGES) r[e] = atomicAdd(&deg[dst[e]], 1);
}

// ---------- exclusive scan over deg (3 kernels) ----------
__global__ __launch_bounds__(256) void scan1_kernel(
    const int* __restrict__ deg, int* __restrict__ excl, int* __restrict__ bsum)
{
    __shared__ int s[256];
    int b = blockIdx.x, t = threadIdx.x;
    int base = b * SCAN_B + t * 4;
    int v[4];
#pragma unroll
    for (int i = 0; i < 4; ++i) v[i] = (base + i < N_NODES) ? deg[base + i] : 0;
    int tsum = v[0] + v[1] + v[2] + v[3];
    s[t] = tsum;
    __syncthreads();
    for (int off = 1; off < 256; off <<= 1) {
        int x = (t >= off) ? s[t - off] : 0;
        __syncthreads();
        s[t] += x;
        __syncthreads();
    }
    int run = s[t] - tsum;          // exclusive prefix of thread sums
#pragma unroll
    for (int i = 0; i < 4; ++i) {
        if (base + i < N_NODES) excl[base + i] = run;
        run += v[i];
    }
    if (t == 255) bsum[b] = s[255];
}

__global__ __launch_bounds__(128) void scan2_kernel(int* __restrict__ bsum)
{
    __shared__ int s[128];
    int t = threadIdx.x;
    int v = (t < SCAN_NB) ? bsum[t] : 0;
    s[t] = v;
    __syncthreads();
    for (int off = 1; off < 128; off <<= 1) {
        int x = (t >= off) ? s[t - off] : 0;
        __syncthreads();
        s[t] += x;
        __syncthreads();
    }
    if (t < SCAN_NB) bsum[t] = s[t] - v;   // exclusive
}

__global__ __launch_bounds__(256) void scan3_kernel(
    const int* __restrict__ excl, const int* __restrict__ bsum,
    int* __restrict__ row_off)
{
    int b = blockIdx.x, t = threadIdx.x;
    int add = bsum[b];
    int base = b * SCAN_B + t * 4;
#pragma unroll
    for (int i = 0; i < 4; ++i)
        if (base + i < N_NODES) row_off[base + i] = excl[base + i] + add;
    if (b == 0 && t == 0) row_off[N_NODES] = N_EDGES;
}

// ---------- bucket edges by dst (no atomics: rank precomputed) ----------
__global__ __launch_bounds__(256) void bucket_kernel(
    const int* __restrict__ src, const int* __restrict__ dst,
    const int* __restrict__ row_off, const int* __restrict__ r,
    int* __restrict__ esrc)
{
    int e = blockIdx.x * 256 + threadIdx.x;
    if (e >= N_EDGES) return;
    int d = dst[e];
    esrc[row_off[d] + r[e]] = src[e];
}

// ---------- y = h @ W  (register-blocked, LDS-swizzled) ----------
// Block: 256 threads, tile = 128 nodes x 64 outputs; thread tile = 4 nodes x 8 outs.
// K processed in passes of 64 (IN/64 passes). XOR swizzle on the k index keyed by
// row bits spreads both read streams across banks (2-way aliasing = free on CDNA4).
template<int IN>
__global__ __launch_bounds__(256) void gemm_kernel(
    const float* __restrict__ h,   // [N, IN]
    const float* __restrict__ W,   // [IN, 64] row-major
    float* __restrict__ y)         // [N, 64]
{
    __shared__ float hs[128 * HSTR];   // h tile: [row][k^key(row)]
    __shared__ float wsh[64 * WSTR];   // W^T tile: [j][k^key(j)]

    const int t = threadIdx.x;
    const int node0 = blockIdx.x * 128;
    const int p = t & 7;        // output group: j0 = p*8
    const int m = t >> 3;       // node group: n0 = m*4  (m in 0..31)

    float acc[4][8];
#pragma unroll
    for (int i = 0; i < 4; ++i)
#pragma unroll
        for (int jj = 0; jj < 8; ++jj) acc[i][jj] = 0.0f;

#pragma unroll
    for (int kb = 0; kb < IN / 64; ++kb) {
        if (kb) __syncthreads();
        // ---- stage h tile: 128 rows x 64 k ----
        {
            int kc = (t & 15) * 4;
            int rbase = t >> 4;               // 0..15
#pragma unroll
            for (int rr = 0; rr < 8; ++rr) {
                int row = rr * 16 + rbase;    // 0..127
                int node = node0 + row;
                float4 v = make_float4(0.f, 0.f, 0.f, 0.f);
                if (node < N_NODES)
                    v = *(const float4*)&h[(size_t)node * IN + kb * 64 + kc];
                int key = ((row >> 2) & 7) * 8;
                *(float4*)&hs[row * HSTR + (kc ^ key)] = v;
            }
        }
        // ---- stage W^T tile: 64 j x 64 k ----
        {
            int j4 = (t & 15) * 4;
            int kbase = t >> 4;               // 0..15
            int wkey = ((j4 >> 3) & 7) * 8;   // uniform over j4..j4+3
#pragma unroll
            for (int it = 0; it < 4; ++it) {
                int k = it * 16 + kbase;      // 0..63
                float4 wv = *(const float4*)&W[(size_t)(kb * 64 + k) * 64 + j4];
                int sk = k ^ wkey;
                wsh[(j4 + 0) * WSTR + sk] = wv.x;
                wsh[(j4 + 1) * WSTR + sk] = wv.y;
                wsh[(j4 + 2) * WSTR + sk] = wv.z;
                wsh[(j4 + 3) * WSTR + sk] = wv.w;
            }
        }
        __syncthreads();

        // ---- compute: 16 k-chunks x 128 FMA ----
        const int hkey = (m & 7) * 8;
        const int wkey = p * 8;
        const float* hb = &hs[(m * 4) * HSTR];
        const float* wb = &wsh[(p * 8) * WSTR];
#pragma unroll
        for (int kc = 0; kc < 64; kc += 4) {
            int hk = kc ^ hkey;
            int wk = kc ^ wkey;
            float4 hv[4], wv[8];
#pragma unroll
            for (int i = 0; i < 4; ++i)  hv[i]  = *(const float4*)&hb[i * HSTR + hk];
#pragma unroll
            for (int jj = 0; jj < 8; ++jj) wv[jj] = *(const float4*)&wb[jj * WSTR + wk];
#pragma unroll
            for (int i = 0; i < 4; ++i)
#pragma unroll
                for (int jj = 0; jj < 8; ++jj) {
                    acc[i][jj] = fmaf(hv[i].x, wv[jj].x, acc[i][jj]);
                    acc[i][jj] = fmaf(hv[i].y, wv[jj].y, acc[i][jj]);
                    acc[i][jj] = fmaf(hv[i].z, wv[jj].z, acc[i][jj]);
                    acc[i][jj] = fmaf(hv[i].w, wv[jj].w, acc[i][jj]);
                }
        }
    }

    // ---- epilogue ----
#pragma unroll
    for (int i = 0; i < 4; ++i) {
        int node = node0 + m * 4 + i;
        if (node >= N_NODES) continue;
        float4 s0 = make_float4(acc[i][0], acc[i][1], acc[i][2], acc[i][3]);
        float4 s1 = make_float4(acc[i][4], acc[i][5], acc[i][6], acc[i][7]);
        *(float4*)&y[(size_t)node * 64 + p * 8]     = s0;
        *(float4*)&y[(size_t)node * 64 + p * 8 + 4] = s1;
    }
}

// ---------- CSR gather-sum + fused GIN epilogue ----------
// out[n] = relu((1+eps)*y[n] + sum_{e in seg(n)} y[esrc[e]] + b)
__global__ __launch_bounds__(256) void aggregate_kernel(
    const float* __restrict__ y,       // [N, 64]
    const int* __restrict__ row_off,   // [N+1]
    const int* __restrict__ esrc,      // [E]
    const float* __restrict__ b,       // [64]
    const float* __restrict__ eps_p,   // [1]
    float* __restrict__ out)           // [N, 64]
{
    int node = blockIdx.x * 4 + (threadIdx.x >> 6);
    int lane = threadIdx.x & 63;
    if (node >= N_NODES) return;
    int s0 = row_off[node], s1 = row_off[node + 1];
    float a0 = 0.f, a1 = 0.f, a2 = 0.f, a3 = 0.f;
    int e = s0;
    for (; e + 4 <= s1; e += 4) {
        int i0 = esrc[e], i1 = esrc[e + 1], i2 = esrc[e + 2], i3 = esrc[e + 3];
        a0 += y[i0 * 64 + lane];
        a1 += y[i1 * 64 + lane];
        a2 += y[i2 * 64 + lane];
        a3 += y[i3 * 64 + lane];
    }
    for (; e < s1; ++e) a0 += y[esrc[e] * 64 + lane];
    float agg = (a0 + a1) + (a2 + a3);
    float v = fmaf(1.0f + eps_p[0], y[node * 64 + lane], agg) + b[lane];
    out[node * 64 + lane] = fmaxf(v, 0.0f);
}

// ---------- mean-pool (sorted batch, binary search) + head MLP ----------
__global__ __launch_bounds__(256) void pool_head_kernel(
    const float* __restrict__ h,      // [N, 64]
    const int* __restrict__ batch,    // [N], sorted
    const float* __restrict__ Wf,     // [64, 10]
    const float* __restrict__ bfv,    // [10]
    const float* __restrict__ Wl,     // [10]
    const float* __restrict__ blv,    // [1]
    float* __restrict__ out)          // [G]
{
    __shared__ float red[4][64];
    __shared__ float pooled[64];
    __shared__ float hid[10];
    int g = blockIdx.x;
    int t = threadIdx.x;
    int lo = 0, hi = N_NODES;
    while (lo < hi) { int mid = (lo + hi) >> 1; if (batch[mid] < g) lo = mid + 1; else hi = mid; }
    int start = lo;
    hi = N_NODES;
    while (lo < hi) { int mid = (lo + hi) >> 1; if (batch[mid] < g + 1) lo = mid + 1; else hi = mid; }
    int end = lo;

    int c = t & 63, nl = t >> 6;
    float acc = 0.0f;
    for (int i = start + nl; i < end; i += 4) acc += h[i * 64 + c];
    red[nl][c] = acc;
    __syncthreads();
    if (t < 64) {
        float cnt = (float)(end - start);
        float inv = 1.0f / fmaxf(cnt, 1.0f);
        pooled[t] = (red[0][t] + red[1][t] + red[2][t] + red[3][t]) * inv;
    }
    __syncthreads();
    if (t < 10) {
        float s = bfv[t];
#pragma unroll
        for (int k = 0; k < 64; ++k) s = fmaf(pooled[k], Wf[k * 10 + t], s);
        hid[t] = fmaxf(s, 0.0f);
    }
    __syncthreads();
    if (t == 0) {
        float s = blv[0];
#pragma unroll
        for (int j = 0; j < 10; ++j) s = fmaf(hid[j], Wl[j], s);
        out[g] = s;
    }
}

extern "C" void kernel_launch(void* const* d_in, const int* in_sizes, int n_in,
                              void* d_out, int out_size, void* d_ws, size_t ws_size,
                              hipStream_t stream)
{
    const float* x     = (const float*)d_in[0];
    const int*   ei    = (const int*)  d_in[1];
    const int*   src   = ei;               // edge_index[0]
    const int*   dst   = ei + N_EDGES;     // edge_index[1]
    const int*   batch = (const int*)  d_in[2];
    const float* W1    = (const float*)d_in[3];
    const float* b1    = (const float*)d_in[4];
    const float* W2    = (const float*)d_in[5];
    const float* b2    = (const float*)d_in[6];
    const float* W3    = (const float*)d_in[7];
    const float* b3    = (const float*)d_in[8];
    const float* Wf    = (const float*)d_in[9];
    const float* bfv   = (const float*)d_in[10];
    const float* Wl    = (const float*)d_in[11];
    const float* blv   = (const float*)d_in[12];
    const float* eps1  = (const float*)d_in[13];
    const float* eps2  = (const float*)d_in[14];
    const float* eps3  = (const float*)d_in[15];

    // ---- workspace layout ----
    float* y    = (float*)d_ws;                 // N*64
    float* h1   = y  + (size_t)N_NODES * 64;    // N*64 (also h3)
    float* h2   = h1 + (size_t)N_NODES * 64;    // N*64
    int*   ints = (int*)(h2 + (size_t)N_NODES * 64);
    int*   deg     = ints;                      // N   (zeroed)
    int*   excl    = deg + N_NODES;             // N
    int*   row_off = excl + N_NODES;            // N+1
    int*   bsum    = row_off + N_NODES + 1;     // 128
    int*   rnk     = bsum + 128;                // E
    int*   esrc    = rnk + N_EDGES;             // E

    // ---- build CSR (dst-sorted edge list), atomic-free bucket ----
    hipMemsetAsync(deg, 0, sizeof(int) * N_NODES, stream);
    hist_kernel<<<N_EDGES / 256, 256, 0, stream>>>(dst, deg, rnk);
    scan1_kernel<<<SCAN_NB, 256, 0, stream>>>(deg, excl, bsum);
    scan2_kernel<<<1, 128, 0, stream>>>(bsum);
    scan3_kernel<<<SCAN_NB, 256, 0, stream>>>(excl, bsum, row_off);
    bucket_kernel<<<N_EDGES / 256, 256, 0, stream>>>(src, dst, row_off, rnk, esrc);

    const int gemm_blk = (N_NODES + 127) / 128;   // 782
    const int agg_blk  = (N_NODES + 3) / 4;

    // ---- layer 1: y = x@W1 ; h1 = relu((1+e1)y + agg(y) + b1) ----
    gemm_kernel<128><<<gemm_blk, 256, 0, stream>>>(x, W1, y);
    aggregate_kernel<<<agg_blk, 256, 0, stream>>>(y, row_off, esrc, b1, eps1, h1);

    // ---- layer 2 ----
    gemm_kernel<64><<<gemm_blk, 256, 0, stream>>>(h1, W2, y);
    aggregate_kernel<<<agg_blk, 256, 0, stream>>>(y, row_off, esrc, b2, eps2, h2);

    // ---- layer 3 (reuse h1 as h3) ----
    gemm_kernel<64><<<gemm_blk, 256, 0, stream>>>(h2, W3, y);
    aggregate_kernel<<<agg_blk, 256, 0, stream>>>(y, row_off, esrc, b3, eps3, h1);

    // ---- pool + head ----
    pool_head_kernel<<<N_GRAPHS, 256, 0, stream>>>(h1, batch, Wf, bfv, Wl, blv,
                                                   (float*)d_out);
}

// Round 4
// 541.576 us; speedup vs baseline: 4.2185x; 4.2185x over previous
//
#include <hip/hip_runtime.h>

#define N_NODES 100000
#define N_EDGES 1600000
#define N_GRAPHS 1000
#define SCAN_B 1024
#define SCAN_NB ((N_NODES + SCAN_B - 1) / SCAN_B)   // 98

#define LSTR 68   // LDS row stride (floats): 68 = 17 banks offset -> worst 2-way aliasing (free)

// ---------- CSR build: histogram of dst + per-edge rank ----------
// rank r[e] = position of edge e within its dst segment (order irrelevant:
// aggregation is a commutative sum), so the bucket pass needs no atomics.
__global__ __launch_bounds__(256) void hist_kernel(
    const int* __restrict__ dst, int* __restrict__ deg, int* __restrict__ r)
{
    int e = blockIdx.x * 256 + threadIdx.x;
    if (e < N_EDGES) r[e] = atomicAdd(&deg[dst[e]], 1);
}

// ---------- exclusive scan over deg (3 kernels) ----------
__global__ __launch_bounds__(256) void scan1_kernel(
    const int* __restrict__ deg, int* __restrict__ excl, int* __restrict__ bsum)
{
    __shared__ int s[256];
    int b = blockIdx.x, t = threadIdx.x;
    int base = b * SCAN_B + t * 4;
    int v[4];
#pragma unroll
    for (int i = 0; i < 4; ++i) v[i] = (base + i < N_NODES) ? deg[base + i] : 0;
    int tsum = v[0] + v[1] + v[2] + v[3];
    s[t] = tsum;
    __syncthreads();
    for (int off = 1; off < 256; off <<= 1) {
        int x = (t >= off) ? s[t - off] : 0;
        __syncthreads();
        s[t] += x;
        __syncthreads();
    }
    int run = s[t] - tsum;          // exclusive prefix of thread sums
#pragma unroll
    for (int i = 0; i < 4; ++i) {
        if (base + i < N_NODES) excl[base + i] = run;
        run += v[i];
    }
    if (t == 255) bsum[b] = s[255];
}

__global__ __launch_bounds__(128) void scan2_kernel(int* __restrict__ bsum)
{
    __shared__ int s[128];
    int t = threadIdx.x;
    int v = (t < SCAN_NB) ? bsum[t] : 0;
    s[t] = v;
    __syncthreads();
    for (int off = 1; off < 128; off <<= 1) {
        int x = (t >= off) ? s[t - off] : 0;
        __syncthreads();
        s[t] += x;
        __syncthreads();
    }
    if (t < SCAN_NB) bsum[t] = s[t] - v;   // exclusive
}

__global__ __launch_bounds__(256) void scan3_kernel(
    const int* __restrict__ excl, const int* __restrict__ bsum,
    int* __restrict__ row_off)
{
    int b = blockIdx.x, t = threadIdx.x;
    int add = bsum[b];
    int base = b * SCAN_B + t * 4;
#pragma unroll
    for (int i = 0; i < 4; ++i)
        if (base + i < N_NODES) row_off[base + i] = excl[base + i] + add;
    if (b == 0 && t == 0) row_off[N_NODES] = N_EDGES;
}

// ---------- bucket edges by dst (no atomics: rank precomputed) ----------
__global__ __launch_bounds__(256) void bucket_kernel(
    const int* __restrict__ src, const int* __restrict__ dst,
    const int* __restrict__ row_off, const int* __restrict__ r,
    int* __restrict__ esrc)
{
    int e = blockIdx.x * 256 + threadIdx.x;
    if (e >= N_EDGES) return;
    int d = dst[e];
    esrc[row_off[d] + r[e]] = src[e];
}

// ---------- y = h @ W  (moderate register blocking; no spills) ----------
// Block: 256 threads, tile = 64 nodes x 64 outputs; thread tile = 4 nodes x 4 outs.
// LDS: h tile [64][64] and W^T tile [64][64], both stride-68 padded (2-way max).
template<int IN>
__global__ __launch_bounds__(256) void gemm_kernel(
    const float* __restrict__ h,   // [N, IN]
    const float* __restrict__ W,   // [IN, 64] row-major
    float* __restrict__ y)         // [N, 64]
{
    __shared__ float hs[64 * LSTR];    // [row][k]
    __shared__ float wsh[64 * LSTR];   // [j][k]   (W transposed)

    const int t = threadIdx.x;
    const int node0 = blockIdx.x * 64;
    const int m = t >> 4;       // 0..15 -> nodes m*4 .. m*4+3
    const int p = t & 15;       // 0..15 -> outputs p*4 .. p*4+3

    float acc[4][4];
#pragma unroll
    for (int i = 0; i < 4; ++i)
#pragma unroll
        for (int j = 0; j < 4; ++j) acc[i][j] = 0.0f;

    for (int kb = 0; kb < IN / 64; ++kb) {
        if (kb) __syncthreads();
        // ---- stage h tile: 64 rows x 64 k (float4 coalesced) ----
        {
            int kc = (t & 15) * 4;
            int rbase = t >> 4;               // 0..15
#pragma unroll
            for (int rr = 0; rr < 4; ++rr) {
                int row = rr * 16 + rbase;
                int node = node0 + row;
                float4 v = make_float4(0.f, 0.f, 0.f, 0.f);
                if (node < N_NODES)
                    v = *(const float4*)&h[(size_t)node * IN + kb * 64 + kc];
                *(float4*)&hs[row * LSTR + kc] = v;
            }
        }
        // ---- stage W^T tile: 64 j x 64 k ----
        {
            int j4 = (t & 15) * 4;
            int kbase = t >> 4;               // 0..15
#pragma unroll
            for (int it = 0; it < 4; ++it) {
                int k = it * 16 + kbase;
                float4 wv = *(const float4*)&W[(size_t)(kb * 64 + k) * 64 + j4];
                wsh[(j4 + 0) * LSTR + k] = wv.x;
                wsh[(j4 + 1) * LSTR + k] = wv.y;
                wsh[(j4 + 2) * LSTR + k] = wv.z;
                wsh[(j4 + 3) * LSTR + k] = wv.w;
            }
        }
        __syncthreads();

        // ---- compute: 16 k-chunks, 8 x ds_read_b128 + 64 FMA each ----
        const float* hb = &hs[(m * 4) * LSTR];
        const float* wb = &wsh[(p * 4) * LSTR];
#pragma unroll 4
        for (int kc = 0; kc < 64; kc += 4) {
            float4 hv[4], wv[4];
#pragma unroll
            for (int i = 0; i < 4; ++i) hv[i] = *(const float4*)&hb[i * LSTR + kc];
#pragma unroll
            for (int j = 0; j < 4; ++j) wv[j] = *(const float4*)&wb[j * LSTR + kc];
#pragma unroll
            for (int i = 0; i < 4; ++i)
#pragma unroll
                for (int j = 0; j < 4; ++j) {
                    acc[i][j] = fmaf(hv[i].x, wv[j].x, acc[i][j]);
                    acc[i][j] = fmaf(hv[i].y, wv[j].y, acc[i][j]);
                    acc[i][j] = fmaf(hv[i].z, wv[j].z, acc[i][j]);
                    acc[i][j] = fmaf(hv[i].w, wv[j].w, acc[i][j]);
                }
        }
    }

    // ---- epilogue: float4 stores ----
#pragma unroll
    for (int i = 0; i < 4; ++i) {
        int node = node0 + m * 4 + i;
        if (node >= N_NODES) continue;
        float4 s = make_float4(acc[i][0], acc[i][1], acc[i][2], acc[i][3]);
        *(float4*)&y[(size_t)node * 64 + p * 4] = s;
    }
}

// ---------- CSR gather-sum + fused GIN epilogue ----------
// out[n] = relu((1+eps)*y[n] + sum_{e in seg(n)} y[esrc[e]] + b)
__global__ __launch_bounds__(256) void aggregate_kernel(
    const float* __restrict__ y,       // [N, 64]
    const int* __restrict__ row_off,   // [N+1]
    const int* __restrict__ esrc,      // [E]
    const float* __restrict__ b,       // [64]
    const float* __restrict__ eps_p,   // [1]
    float* __restrict__ out)           // [N, 64]
{
    int node = blockIdx.x * 4 + (threadIdx.x >> 6);
    int lane = threadIdx.x & 63;
    if (node >= N_NODES) return;
    int s0 = row_off[node], s1 = row_off[node + 1];
    float a0 = 0.f, a1 = 0.f, a2 = 0.f, a3 = 0.f;
    int e = s0;
    for (; e + 4 <= s1; e += 4) {
        int i0 = esrc[e], i1 = esrc[e + 1], i2 = esrc[e + 2], i3 = esrc[e + 3];
        a0 += y[i0 * 64 + lane];
        a1 += y[i1 * 64 + lane];
        a2 += y[i2 * 64 + lane];
        a3 += y[i3 * 64 + lane];
    }
    for (; e < s1; ++e) a0 += y[esrc[e] * 64 + lane];
    float agg = (a0 + a1) + (a2 + a3);
    float v = fmaf(1.0f + eps_p[0], y[node * 64 + lane], agg) + b[lane];
    out[node * 64 + lane] = fmaxf(v, 0.0f);
}

// ---------- mean-pool (sorted batch, binary search) + head MLP ----------
__global__ __launch_bounds__(256) void pool_head_kernel(
    const float* __restrict__ h,      // [N, 64]
    const int* __restrict__ batch,    // [N], sorted
    const float* __restrict__ Wf,     // [64, 10]
    const float* __restrict__ bfv,    // [10]
    const float* __restrict__ Wl,     // [10]
    const float* __restrict__ blv,    // [1]
    float* __restrict__ out)          // [G]
{
    __shared__ float red[4][64];
    __shared__ float pooled[64];
    __shared__ float hid[10];
    int g = blockIdx.x;
    int t = threadIdx.x;
    int lo = 0, hi = N_NODES;
    while (lo < hi) { int mid = (lo + hi) >> 1; if (batch[mid] < g) lo = mid + 1; else hi = mid; }
    int start = lo;
    hi = N_NODES;
    while (lo < hi) { int mid = (lo + hi) >> 1; if (batch[mid] < g + 1) lo = mid + 1; else hi = mid; }
    int end = lo;

    int c = t & 63, nl = t >> 6;
    float acc = 0.0f;
    for (int i = start + nl; i < end; i += 4) acc += h[i * 64 + c];
    red[nl][c] = acc;
    __syncthreads();
    if (t < 64) {
        float cnt = (float)(end - start);
        float inv = 1.0f / fmaxf(cnt, 1.0f);
        pooled[t] = (red[0][t] + red[1][t] + red[2][t] + red[3][t]) * inv;
    }
    __syncthreads();
    if (t < 10) {
        float s = bfv[t];
#pragma unroll
        for (int k = 0; k < 64; ++k) s = fmaf(pooled[k], Wf[k * 10 + t], s);
        hid[t] = fmaxf(s, 0.0f);
    }
    __syncthreads();
    if (t == 0) {
        float s = blv[0];
#pragma unroll
        for (int j = 0; j < 10; ++j) s = fmaf(hid[j], Wl[j], s);
        out[g] = s;
    }
}

extern "C" void kernel_launch(void* const* d_in, const int* in_sizes, int n_in,
                              void* d_out, int out_size, void* d_ws, size_t ws_size,
                              hipStream_t stream)
{
    const float* x     = (const float*)d_in[0];
    const int*   ei    = (const int*)  d_in[1];
    const int*   src   = ei;               // edge_index[0]
    const int*   dst   = ei + N_EDGES;     // edge_index[1]
    const int*   batch = (const int*)  d_in[2];
    const float* W1    = (const float*)d_in[3];
    const float* b1    = (const float*)d_in[4];
    const float* W2    = (const float*)d_in[5];
    const float* b2    = (const float*)d_in[6];
    const float* W3    = (const float*)d_in[7];
    const float* b3    = (const float*)d_in[8];
    const float* Wf    = (const float*)d_in[9];
    const float* bfv   = (const float*)d_in[10];
    const float* Wl    = (const float*)d_in[11];
    const float* blv   = (const float*)d_in[12];
    const float* eps1  = (const float*)d_in[13];
    const float* eps2  = (const float*)d_in[14];
    const float* eps3  = (const float*)d_in[15];

    // ---- workspace layout ----
    float* y    = (float*)d_ws;                 // N*64
    float* h1   = y  + (size_t)N_NODES * 64;    // N*64 (also h3)
    float* h2   = h1 + (size_t)N_NODES * 64;    // N*64
    int*   ints = (int*)(h2 + (size_t)N_NODES * 64);
    int*   deg     = ints;                      // N   (zeroed)
    int*   excl    = deg + N_NODES;             // N
    int*   row_off = excl + N_NODES;            // N+1
    int*   bsum    = row_off + N_NODES + 1;     // 128
    int*   rnk     = bsum + 128;                // E
    int*   esrc    = rnk + N_EDGES;             // E

    // ---- build CSR (dst-sorted edge list), atomic-free bucket ----
    hipMemsetAsync(deg, 0, sizeof(int) * N_NODES, stream);
    hist_kernel<<<N_EDGES / 256, 256, 0, stream>>>(dst, deg, rnk);
    scan1_kernel<<<SCAN_NB, 256, 0, stream>>>(deg, excl, bsum);
    scan2_kernel<<<1, 128, 0, stream>>>(bsum);
    scan3_kernel<<<SCAN_NB, 256, 0, stream>>>(excl, bsum, row_off);
    bucket_kernel<<<N_EDGES / 256, 256, 0, stream>>>(src, dst, row_off, rnk, esrc);

    const int gemm_blk = (N_NODES + 63) / 64;    // 1563
    const int agg_blk  = (N_NODES + 3) / 4;

    // ---- layer 1: y = x@W1 ; h1 = relu((1+e1)y + agg(y) + b1) ----
    gemm_kernel<128><<<gemm_blk, 256, 0, stream>>>(x, W1, y);
    aggregate_kernel<<<agg_blk, 256, 0, stream>>>(y, row_off, esrc, b1, eps1, h1);

    // ---- layer 2 ----
    gemm_kernel<64><<<gemm_blk, 256, 0, stream>>>(h1, W2, y);
    aggregate_kernel<<<agg_blk, 256, 0, stream>>>(y, row_off, esrc, b2, eps2, h2);

    // ---- layer 3 (reuse h1 as h3) ----
    gemm_kernel<64><<<gemm_blk, 256, 0, stream>>>(h2, W3, y);
    aggregate_kernel<<<agg_blk, 256, 0, stream>>>(y, row_off, esrc, b3, eps3, h1);

    // ---- pool + head ----
    pool_head_kernel<<<N_GRAPHS, 256, 0, stream>>>(h1, batch, Wf, bfv, Wl, blv,
                                                   (float*)d_out);
}

// Round 5
// 503.869 us; speedup vs baseline: 4.5341x; 1.0748x over previous
//
#include <hip/hip_runtime.h>

#define N_NODES 100000
#define N_EDGES 1600000
#define N_GRAPHS 1000
#define SCAN_B 1024
#define SCAN_NB ((N_NODES + SCAN_B - 1) / SCAN_B)   // 98

#define LSTR 68   // LDS row stride (floats): worst-case 2-way bank aliasing (free on CDNA4)

typedef unsigned int uint32;
typedef unsigned short ushort16;

// float -> bf16 with round-to-nearest-even
static __device__ __forceinline__ ushort16 f2bf(float f) {
    uint32 u = __float_as_uint(f);
    u += 0x7fffu + ((u >> 16) & 1u);
    return (ushort16)(u >> 16);
}
// unpack a bf16x2 word into two floats (lo = even channel, hi = odd channel)
static __device__ __forceinline__ void bf2x(uint32 v, float& lo, float& hi) {
    lo = __uint_as_float(v << 16);
    hi = __uint_as_float(v & 0xffff0000u);
}

// ---------- CSR build: histogram of dst + per-edge rank ----------
__global__ __launch_bounds__(256) void hist_kernel(
    const int* __restrict__ dst, int* __restrict__ deg, int* __restrict__ r)
{
    int e = blockIdx.x * 256 + threadIdx.x;
    if (e < N_EDGES) r[e] = atomicAdd(&deg[dst[e]], 1);
}

// ---------- exclusive scan over deg (3 kernels) ----------
__global__ __launch_bounds__(256) void scan1_kernel(
    const int* __restrict__ deg, int* __restrict__ excl, int* __restrict__ bsum)
{
    __shared__ int s[256];
    int b = blockIdx.x, t = threadIdx.x;
    int base = b * SCAN_B + t * 4;
    int v[4];
#pragma unroll
    for (int i = 0; i < 4; ++i) v[i] = (base + i < N_NODES) ? deg[base + i] : 0;
    int tsum = v[0] + v[1] + v[2] + v[3];
    s[t] = tsum;
    __syncthreads();
    for (int off = 1; off < 256; off <<= 1) {
        int x = (t >= off) ? s[t - off] : 0;
        __syncthreads();
        s[t] += x;
        __syncthreads();
    }
    int run = s[t] - tsum;
#pragma unroll
    for (int i = 0; i < 4; ++i) {
        if (base + i < N_NODES) excl[base + i] = run;
        run += v[i];
    }
    if (t == 255) bsum[b] = s[255];
}

__global__ __launch_bounds__(128) void scan2_kernel(int* __restrict__ bsum)
{
    __shared__ int s[128];
    int t = threadIdx.x;
    int v = (t < SCAN_NB) ? bsum[t] : 0;
    s[t] = v;
    __syncthreads();
    for (int off = 1; off < 128; off <<= 1) {
        int x = (t >= off) ? s[t - off] : 0;
        __syncthreads();
        s[t] += x;
        __syncthreads();
    }
    if (t < SCAN_NB) bsum[t] = s[t] - v;
}

__global__ __launch_bounds__(256) void scan3_kernel(
    const int* __restrict__ excl, const int* __restrict__ bsum,
    int* __restrict__ row_off)
{
    int b = blockIdx.x, t = threadIdx.x;
    int add = bsum[b];
    int base = b * SCAN_B + t * 4;
#pragma unroll
    for (int i = 0; i < 4; ++i)
        if (base + i < N_NODES) row_off[base + i] = excl[base + i] + add;
    if (b == 0 && t == 0) row_off[N_NODES] = N_EDGES;
}

// ---------- bucket edges by dst (no atomics: rank precomputed) ----------
__global__ __launch_bounds__(256) void bucket_kernel(
    const int* __restrict__ src, const int* __restrict__ dst,
    const int* __restrict__ row_off, const int* __restrict__ r,
    int* __restrict__ esrc)
{
    int e = blockIdx.x * 256 + threadIdx.x;
    if (e >= N_EDGES) return;
    int d = dst[e];
    esrc[row_off[d] + r[e]] = src[e];
}

// ---------- y(bf16) = h @ W ----------
// Block: 256 threads, tile = 64 nodes x 64 outputs; thread tile = 4 nodes x 4 outs.
template<int IN>
__global__ __launch_bounds__(256) void gemm_kernel(
    const float* __restrict__ h,   // [N, IN] fp32
    const float* __restrict__ W,   // [IN, 64] row-major
    ushort16* __restrict__ y)      // [N, 64] bf16
{
    __shared__ float hs[64 * LSTR];
    __shared__ float wsh[64 * LSTR];

    const int t = threadIdx.x;
    const int node0 = blockIdx.x * 64;
    const int m = t >> 4;
    const int p = t & 15;

    float acc[4][4];
#pragma unroll
    for (int i = 0; i < 4; ++i)
#pragma unroll
        for (int j = 0; j < 4; ++j) acc[i][j] = 0.0f;

    for (int kb = 0; kb < IN / 64; ++kb) {
        if (kb) __syncthreads();
        {
            int kc = (t & 15) * 4;
            int rbase = t >> 4;
#pragma unroll
            for (int rr = 0; rr < 4; ++rr) {
                int row = rr * 16 + rbase;
                int node = node0 + row;
                float4 v = make_float4(0.f, 0.f, 0.f, 0.f);
                if (node < N_NODES)
                    v = *(const float4*)&h[(size_t)node * IN + kb * 64 + kc];
                *(float4*)&hs[row * LSTR + kc] = v;
            }
        }
        {
            int j4 = (t & 15) * 4;
            int kbase = t >> 4;
#pragma unroll
            for (int it = 0; it < 4; ++it) {
                int k = it * 16 + kbase;
                float4 wv = *(const float4*)&W[(size_t)(kb * 64 + k) * 64 + j4];
                wsh[(j4 + 0) * LSTR + k] = wv.x;
                wsh[(j4 + 1) * LSTR + k] = wv.y;
                wsh[(j4 + 2) * LSTR + k] = wv.z;
                wsh[(j4 + 3) * LSTR + k] = wv.w;
            }
        }
        __syncthreads();

        const float* hb = &hs[(m * 4) * LSTR];
        const float* wb = &wsh[(p * 4) * LSTR];
#pragma unroll 4
        for (int kc = 0; kc < 64; kc += 4) {
            float4 hv[4], wv[4];
#pragma unroll
            for (int i = 0; i < 4; ++i) hv[i] = *(const float4*)&hb[i * LSTR + kc];
#pragma unroll
            for (int j = 0; j < 4; ++j) wv[j] = *(const float4*)&wb[j * LSTR + kc];
#pragma unroll
            for (int i = 0; i < 4; ++i)
#pragma unroll
                for (int j = 0; j < 4; ++j) {
                    acc[i][j] = fmaf(hv[i].x, wv[j].x, acc[i][j]);
                    acc[i][j] = fmaf(hv[i].y, wv[j].y, acc[i][j]);
                    acc[i][j] = fmaf(hv[i].z, wv[j].z, acc[i][j]);
                    acc[i][j] = fmaf(hv[i].w, wv[j].w, acc[i][j]);
                }
        }
    }

    // ---- epilogue: pack bf16x4 (8 B) stores ----
#pragma unroll
    for (int i = 0; i < 4; ++i) {
        int node = node0 + m * 4 + i;
        if (node >= N_NODES) continue;
        uint32 w0 = (uint32)f2bf(acc[i][0]) | ((uint32)f2bf(acc[i][1]) << 16);
        uint32 w1 = (uint32)f2bf(acc[i][2]) | ((uint32)f2bf(acc[i][3]) << 16);
        uint2 pk = make_uint2(w0, w1);
        *(uint2*)&y[(size_t)node * 64 + p * 4] = pk;
    }
}

// ---------- CSR gather-sum (bf16 rows) + fused GIN epilogue ----------
// Wave = 1 node. Lane l: half = l>>5 (which edge of the pair), c2 = l&31
// (bf16x2 channel pair). Two 32-lane halves process 2 edges per step; the
// halves' partial sums combine via shfl_xor(32) at the end.
__global__ __launch_bounds__(256) void aggregate_kernel(
    const uint32* __restrict__ y,      // [N, 32] bf16x2 words
    const int* __restrict__ row_off,   // [N+1]
    const int* __restrict__ esrc,      // [E]
    const float* __restrict__ b,       // [64]
    const float* __restrict__ eps_p,   // [1]
    float* __restrict__ out)           // [N, 64] fp32
{
    int node = blockIdx.x * 4 + (threadIdx.x >> 6);
    int lane = threadIdx.x & 63;
    int half = lane >> 5;
    int c2   = lane & 31;
    if (node >= N_NODES) return;

    int s0 = row_off[node], s1 = row_off[node + 1];
    float ax0 = 0.f, ay0 = 0.f, ax1 = 0.f, ay1 = 0.f;
    int e = s0 + half;
    for (; e + 2 < s1; e += 4) {
        int i0 = esrc[e];
        int i1 = esrc[e + 2];
        uint32 v0 = y[i0 * 32 + c2];
        uint32 v1 = y[i1 * 32 + c2];
        float l0, h0, l1, h1;
        bf2x(v0, l0, h0);
        bf2x(v1, l1, h1);
        ax0 += l0; ay0 += h0;
        ax1 += l1; ay1 += h1;
    }
    if (e < s1) {
        int i0 = esrc[e];
        float l0, h0;
        bf2x(y[i0 * 32 + c2], l0, h0);
        ax0 += l0; ay0 += h0;
    }
    float ax = ax0 + ax1;
    float ay = ay0 + ay1;
    ax += __shfl_xor(ax, 32);
    ay += __shfl_xor(ay, 32);

    // self term + bias + relu (computed redundantly on both halves; half 0 stores)
    float sl, sh;
    bf2x(y[node * 32 + c2], sl, sh);
    float ep1 = 1.0f + eps_p[0];
    float2 bb = *(const float2*)&b[c2 * 2];
    float r0 = fmaxf(fmaf(ep1, sl, ax) + bb.x, 0.0f);
    float r1 = fmaxf(fmaf(ep1, sh, ay) + bb.y, 0.0f);
    if (half == 0)
        *(float2*)&out[(size_t)node * 64 + c2 * 2] = make_float2(r0, r1);
}

// ---------- mean-pool (sorted batch, binary search) + head MLP ----------
__global__ __launch_bounds__(256) void pool_head_kernel(
    const float* __restrict__ h,      // [N, 64]
    const int* __restrict__ batch,    // [N], sorted
    const float* __restrict__ Wf,     // [64, 10]
    const float* __restrict__ bfv,    // [10]
    const float* __restrict__ Wl,     // [10]
    const float* __restrict__ blv,    // [1]
    float* __restrict__ out)          // [G]
{
    __shared__ float red[4][64];
    __shared__ float pooled[64];
    __shared__ float hid[10];
    int g = blockIdx.x;
    int t = threadIdx.x;
    int lo = 0, hi = N_NODES;
    while (lo < hi) { int mid = (lo + hi) >> 1; if (batch[mid] < g) lo = mid + 1; else hi = mid; }
    int start = lo;
    hi = N_NODES;
    while (lo < hi) { int mid = (lo + hi) >> 1; if (batch[mid] < g + 1) lo = mid + 1; else hi = mid; }
    int end = lo;

    int c = t & 63, nl = t >> 6;
    float acc = 0.0f;
    for (int i = start + nl; i < end; i += 4) acc += h[i * 64 + c];
    red[nl][c] = acc;
    __syncthreads();
    if (t < 64) {
        float cnt = (float)(end - start);
        float inv = 1.0f / fmaxf(cnt, 1.0f);
        pooled[t] = (red[0][t] + red[1][t] + red[2][t] + red[3][t]) * inv;
    }
    __syncthreads();
    if (t < 10) {
        float s = bfv[t];
#pragma unroll
        for (int k = 0; k < 64; ++k) s = fmaf(pooled[k], Wf[k * 10 + t], s);
        hid[t] = fmaxf(s, 0.0f);
    }
    __syncthreads();
    if (t == 0) {
        float s = blv[0];
#pragma unroll
        for (int j = 0; j < 10; ++j) s = fmaf(hid[j], Wl[j], s);
        out[g] = s;
    }
}

extern "C" void kernel_launch(void* const* d_in, const int* in_sizes, int n_in,
                              void* d_out, int out_size, void* d_ws, size_t ws_size,
                              hipStream_t stream)
{
    const float* x     = (const float*)d_in[0];
    const int*   ei    = (const int*)  d_in[1];
    const int*   src   = ei;               // edge_index[0]
    const int*   dst   = ei + N_EDGES;     // edge_index[1]
    const int*   batch = (const int*)  d_in[2];
    const float* W1    = (const float*)d_in[3];
    const float* b1    = (const float*)d_in[4];
    const float* W2    = (const float*)d_in[5];
    const float* b2    = (const float*)d_in[6];
    const float* W3    = (const float*)d_in[7];
    const float* b3    = (const float*)d_in[8];
    const float* Wf    = (const float*)d_in[9];
    const float* bfv   = (const float*)d_in[10];
    const float* Wl    = (const float*)d_in[11];
    const float* blv   = (const float*)d_in[12];
    const float* eps1  = (const float*)d_in[13];
    const float* eps2  = (const float*)d_in[14];
    const float* eps3  = (const float*)d_in[15];

    // ---- workspace layout ----
    ushort16* ybf = (ushort16*)d_ws;                       // N*64 bf16 (12.8 MB)
    float* h1   = (float*)(ybf + (size_t)N_NODES * 64);    // N*64 fp32 (also h3)
    float* h2   = h1 + (size_t)N_NODES * 64;               // N*64 fp32
    int*   ints = (int*)(h2 + (size_t)N_NODES * 64);
    int*   deg     = ints;                      // N   (zeroed)
    int*   excl    = deg + N_NODES;             // N
    int*   row_off = excl + N_NODES;            // N+1
    int*   bsum    = row_off + N_NODES + 1;     // 128
    int*   rnk     = bsum + 128;                // E
    int*   esrc    = rnk + N_EDGES;             // E

    // ---- build CSR (dst-sorted edge list), atomic-free bucket ----
    hipMemsetAsync(deg, 0, sizeof(int) * N_NODES, stream);
    hist_kernel<<<N_EDGES / 256, 256, 0, stream>>>(dst, deg, rnk);
    scan1_kernel<<<SCAN_NB, 256, 0, stream>>>(deg, excl, bsum);
    scan2_kernel<<<1, 128, 0, stream>>>(bsum);
    scan3_kernel<<<SCAN_NB, 256, 0, stream>>>(excl, bsum, row_off);
    bucket_kernel<<<N_EDGES / 256, 256, 0, stream>>>(src, dst, row_off, rnk, esrc);

    const int gemm_blk = (N_NODES + 63) / 64;    // 1563
    const int agg_blk  = (N_NODES + 3) / 4;

    // ---- layer 1: y = x@W1 ; h1 = relu((1+e1)y + agg(y) + b1) ----
    gemm_kernel<128><<<gemm_blk, 256, 0, stream>>>(x, W1, ybf);
    aggregate_kernel<<<agg_blk, 256, 0, stream>>>((const uint32*)ybf, row_off, esrc, b1, eps1, h1);

    // ---- layer 2 ----
    gemm_kernel<64><<<gemm_blk, 256, 0, stream>>>(h1, W2, ybf);
    aggregate_kernel<<<agg_blk, 256, 0, stream>>>((const uint32*)ybf, row_off, esrc, b2, eps2, h2);

    // ---- layer 3 (reuse h1 as h3) ----
    gemm_kernel<64><<<gemm_blk, 256, 0, stream>>>(h2, W3, ybf);
    aggregate_kernel<<<agg_blk, 256, 0, stream>>>((const uint32*)ybf, row_off, esrc, b3, eps3, h1);

    // ---- pool + head ----
    pool_head_kernel<<<N_GRAPHS, 256, 0, stream>>>(h1, batch, Wf, bfv, Wl, blv,
                                                   (float*)d_out);
}

// Round 6
// 453.185 us; speedup vs baseline: 5.0412x; 1.1118x over previous
//
#include <hip/hip_runtime.h>

#define N_NODES 100000
#define N_EDGES 1600000
#define N_GRAPHS 1000

#define NB_C 782                 // coarse buckets: dst>>7, 128 nodes each
#define B1   256                 // blocks in count/scatter phases
#define CHUNK (N_EDGES / B1)     // 6250 (exact)
#define MTOT (NB_C * B1)         // 200192 count-matrix entries

#define LSTR 68   // LDS row stride (floats): worst-case 2-way bank aliasing (free on CDNA4)

typedef unsigned int uint32;
typedef unsigned short ushort16;

// float -> bf16 with round-to-nearest-even
static __device__ __forceinline__ ushort16 f2bf(float f) {
    uint32 u = __float_as_uint(f);
    u += 0x7fffu + ((u >> 16) & 1u);
    return (ushort16)(u >> 16);
}
// unpack a bf16x2 word into two floats (lo = even channel, hi = odd channel)
static __device__ __forceinline__ void bf2x(uint32 v, float& lo, float& hi) {
    lo = __uint_as_float(v << 16);
    hi = __uint_as_float(v & 0xffff0000u);
}

// ============ CSR build: two-level counting sort (LDS atomics only) ============

// K1: per-block LDS histogram over coarse buckets -> M[q*B1 + b]
__global__ __launch_bounds__(256) void count_kernel(
    const int* __restrict__ dst, int* __restrict__ M)
{
    __shared__ int cnt[NB_C];
    int b = blockIdx.x, t = threadIdx.x;
    for (int q = t; q < NB_C; q += 256) cnt[q] = 0;
    __syncthreads();
    int e0 = b * CHUNK;
    for (int e = e0 + t; e < e0 + CHUNK; e += 256)
        atomicAdd(&cnt[dst[e] >> 7], 1);
    __syncthreads();
    for (int q = t; q < NB_C; q += 256) M[q * B1 + b] = cnt[q];
}

// K2: exclusive scan of M (MTOT elements), 3-kernel hierarchy
#define SCAN_B 1024
#define SCAN_NBLK ((MTOT + SCAN_B - 1) / SCAN_B)   // 196

__global__ __launch_bounds__(256) void scanA_kernel(
    const int* __restrict__ in, int* __restrict__ excl, int* __restrict__ bsum)
{
    __shared__ int s[256];
    int b = blockIdx.x, t = threadIdx.x;
    int base = b * SCAN_B + t * 4;
    int v[4];
#pragma unroll
    for (int i = 0; i < 4; ++i) v[i] = (base + i < MTOT) ? in[base + i] : 0;
    int tsum = v[0] + v[1] + v[2] + v[3];
    s[t] = tsum;
    __syncthreads();
    for (int off = 1; off < 256; off <<= 1) {
        int x = (t >= off) ? s[t - off] : 0;
        __syncthreads();
        s[t] += x;
        __syncthreads();
    }
    int run = s[t] - tsum;
#pragma unroll
    for (int i = 0; i < 4; ++i) {
        if (base + i < MTOT) excl[base + i] = run;
        run += v[i];
    }
    if (t == 255) bsum[b] = s[255];
}

__global__ __launch_bounds__(256) void scanB_kernel(int* __restrict__ bsum)
{
    __shared__ int s[256];
    int t = threadIdx.x;
    int v = (t < SCAN_NBLK) ? bsum[t] : 0;
    s[t] = v;
    __syncthreads();
    for (int off = 1; off < 256; off <<= 1) {
        int x = (t >= off) ? s[t - off] : 0;
        __syncthreads();
        s[t] += x;
        __syncthreads();
    }
    if (t < SCAN_NBLK) bsum[t] = s[t] - v;   // exclusive
}

__global__ __launch_bounds__(256) void scanC_kernel(
    const int* __restrict__ excl, const int* __restrict__ bsum,
    int* __restrict__ out)
{
    int b = blockIdx.x, t = threadIdx.x;
    int add = bsum[b];
    int base = b * SCAN_B + t * 4;
#pragma unroll
    for (int i = 0; i < 4; ++i)
        if (base + i < MTOT) out[base + i] = excl[base + i] + add;
}

// K3: scatter edges into coarse-bucket-sorted tmp; packed (local<<17)|src.
// Each (block,bucket) run is contiguous -> writes combine in L2.
__global__ __launch_bounds__(256) void scatter_kernel(
    const int* __restrict__ src, const int* __restrict__ dst,
    const int* __restrict__ Ms, uint32* __restrict__ tmp)
{
    __shared__ int cur[NB_C];
    int b = blockIdx.x, t = threadIdx.x;
    for (int q = t; q < NB_C; q += 256) cur[q] = Ms[q * B1 + b];
    __syncthreads();
    int e0 = b * CHUNK;
    for (int e = e0 + t; e < e0 + CHUNK; e += 256) {
        int d = dst[e];
        int q = d >> 7;
        int pos = atomicAdd(&cur[q], 1);
        tmp[pos] = ((uint32)(d & 127) << 17) | (uint32)src[e];
    }
}

// K4: per-bucket local counting sort -> row_off + esrc (8 KB window, L2-resident)
__global__ __launch_bounds__(256) void finalize_kernel(
    const uint32* __restrict__ tmp, const int* __restrict__ Ms,
    int* __restrict__ row_off, int* __restrict__ esrc)
{
    __shared__ int cnt[128];
    __shared__ int pref[128];
    __shared__ int cur[128];
    int q = blockIdx.x, t = threadIdx.x;
    int start = Ms[q * B1];
    int end = (q == NB_C - 1) ? N_EDGES : Ms[(q + 1) * B1];

    if (t < 128) cnt[t] = 0;
    __syncthreads();
    for (int e = start + t; e < end; e += 256)
        atomicAdd(&cnt[tmp[e] >> 17], 1);
    __syncthreads();
    // Hillis-Steele inclusive scan of cnt -> pref
    if (t < 128) pref[t] = cnt[t];
    __syncthreads();
    for (int off = 1; off < 128; off <<= 1) {
        int x = 0;
        if (t < 128 && t >= off) x = pref[t - off];
        __syncthreads();
        if (t < 128) pref[t] += x;
        __syncthreads();
    }
    if (t < 128) {
        int excl = pref[t] - cnt[t];
        int node = q * 128 + t;
        if (node < N_NODES) row_off[node] = start + excl;
        cur[t] = start + excl;
    }
    if (q == 0 && t == 0) row_off[N_NODES] = N_EDGES;
    __syncthreads();
    for (int e = start + t; e < end; e += 256) {
        uint32 u = tmp[e];
        int pos = atomicAdd(&cur[u >> 17], 1);
        esrc[pos] = (int)(u & 0x1FFFFu);
    }
}

// ============ y(bf16) = h @ W ============
// Block: 256 threads, tile = 64 nodes x 64 outputs; thread tile = 4 nodes x 4 outs.
template<int IN>
__global__ __launch_bounds__(256) void gemm_kernel(
    const float* __restrict__ h,   // [N, IN] fp32
    const float* __restrict__ W,   // [IN, 64] row-major
    ushort16* __restrict__ y)      // [N, 64] bf16
{
    __shared__ float hs[64 * LSTR];
    __shared__ float wsh[64 * LSTR];

    const int t = threadIdx.x;
    const int node0 = blockIdx.x * 64;
    const int m = t >> 4;
    const int p = t & 15;

    float acc[4][4];
#pragma unroll
    for (int i = 0; i < 4; ++i)
#pragma unroll
        for (int j = 0; j < 4; ++j) acc[i][j] = 0.0f;

    for (int kb = 0; kb < IN / 64; ++kb) {
        if (kb) __syncthreads();
        {
            int kc = (t & 15) * 4;
            int rbase = t >> 4;
#pragma unroll
            for (int rr = 0; rr < 4; ++rr) {
                int row = rr * 16 + rbase;
                int node = node0 + row;
                float4 v = make_float4(0.f, 0.f, 0.f, 0.f);
                if (node < N_NODES)
                    v = *(const float4*)&h[(size_t)node * IN + kb * 64 + kc];
                *(float4*)&hs[row * LSTR + kc] = v;
            }
        }
        {
            int j4 = (t & 15) * 4;
            int kbase = t >> 4;
#pragma unroll
            for (int it = 0; it < 4; ++it) {
                int k = it * 16 + kbase;
                float4 wv = *(const float4*)&W[(size_t)(kb * 64 + k) * 64 + j4];
                wsh[(j4 + 0) * LSTR + k] = wv.x;
                wsh[(j4 + 1) * LSTR + k] = wv.y;
                wsh[(j4 + 2) * LSTR + k] = wv.z;
                wsh[(j4 + 3) * LSTR + k] = wv.w;
            }
        }
        __syncthreads();

        const float* hb = &hs[(m * 4) * LSTR];
        const float* wb = &wsh[(p * 4) * LSTR];
#pragma unroll 4
        for (int kc = 0; kc < 64; kc += 4) {
            float4 hv[4], wv[4];
#pragma unroll
            for (int i = 0; i < 4; ++i) hv[i] = *(const float4*)&hb[i * LSTR + kc];
#pragma unroll
            for (int j = 0; j < 4; ++j) wv[j] = *(const float4*)&wb[j * LSTR + kc];
#pragma unroll
            for (int i = 0; i < 4; ++i)
#pragma unroll
                for (int j = 0; j < 4; ++j) {
                    acc[i][j] = fmaf(hv[i].x, wv[j].x, acc[i][j]);
                    acc[i][j] = fmaf(hv[i].y, wv[j].y, acc[i][j]);
                    acc[i][j] = fmaf(hv[i].z, wv[j].z, acc[i][j]);
                    acc[i][j] = fmaf(hv[i].w, wv[j].w, acc[i][j]);
                }
        }
    }

#pragma unroll
    for (int i = 0; i < 4; ++i) {
        int node = node0 + m * 4 + i;
        if (node >= N_NODES) continue;
        uint32 w0 = (uint32)f2bf(acc[i][0]) | ((uint32)f2bf(acc[i][1]) << 16);
        uint32 w1 = (uint32)f2bf(acc[i][2]) | ((uint32)f2bf(acc[i][3]) << 16);
        uint2 pk = make_uint2(w0, w1);
        *(uint2*)&y[(size_t)node * 64 + p * 4] = pk;
    }
}

// ============ CSR gather-sum (bf16 rows) + fused GIN epilogue ============
__global__ __launch_bounds__(256) void aggregate_kernel(
    const uint32* __restrict__ y,      // [N, 32] bf16x2 words
    const int* __restrict__ row_off,   // [N+1]
    const int* __restrict__ esrc,      // [E]
    const float* __restrict__ b,       // [64]
    const float* __restrict__ eps_p,   // [1]
    float* __restrict__ out)           // [N, 64] fp32
{
    int node = blockIdx.x * 4 + (threadIdx.x >> 6);
    int lane = threadIdx.x & 63;
    int half = lane >> 5;
    int c2   = lane & 31;
    if (node >= N_NODES) return;

    int s0 = row_off[node], s1 = row_off[node + 1];
    float ax0 = 0.f, ay0 = 0.f, ax1 = 0.f, ay1 = 0.f;
    int e = s0 + half;
    for (; e + 2 < s1; e += 4) {
        int i0 = esrc[e];
        int i1 = esrc[e + 2];
        uint32 v0 = y[i0 * 32 + c2];
        uint32 v1 = y[i1 * 32 + c2];
        float l0, h0, l1, h1;
        bf2x(v0, l0, h0);
        bf2x(v1, l1, h1);
        ax0 += l0; ay0 += h0;
        ax1 += l1; ay1 += h1;
    }
    if (e < s1) {
        int i0 = esrc[e];
        float l0, h0;
        bf2x(y[i0 * 32 + c2], l0, h0);
        ax0 += l0; ay0 += h0;
    }
    float ax = ax0 + ax1;
    float ay = ay0 + ay1;
    ax += __shfl_xor(ax, 32);
    ay += __shfl_xor(ay, 32);

    float sl, sh;
    bf2x(y[node * 32 + c2], sl, sh);
    float ep1 = 1.0f + eps_p[0];
    float2 bb = *(const float2*)&b[c2 * 2];
    float r0 = fmaxf(fmaf(ep1, sl, ax) + bb.x, 0.0f);
    float r1 = fmaxf(fmaf(ep1, sh, ay) + bb.y, 0.0f);
    if (half == 0)
        *(float2*)&out[(size_t)node * 64 + c2 * 2] = make_float2(r0, r1);
}

// ============ mean-pool (sorted batch, binary search) + head MLP ============
__global__ __launch_bounds__(256) void pool_head_kernel(
    const float* __restrict__ h,      // [N, 64]
    const int* __restrict__ batch,    // [N], sorted
    const float* __restrict__ Wf,     // [64, 10]
    const float* __restrict__ bfv,    // [10]
    const float* __restrict__ Wl,     // [10]
    const float* __restrict__ blv,    // [1]
    float* __restrict__ out)          // [G]
{
    __shared__ float red[4][64];
    __shared__ float pooled[64];
    __shared__ float hid[10];
    int g = blockIdx.x;
    int t = threadIdx.x;
    int lo = 0, hi = N_NODES;
    while (lo < hi) { int mid = (lo + hi) >> 1; if (batch[mid] < g) lo = mid + 1; else hi = mid; }
    int start = lo;
    hi = N_NODES;
    while (lo < hi) { int mid = (lo + hi) >> 1; if (batch[mid] < g + 1) lo = mid + 1; else hi = mid; }
    int end = lo;

    int c = t & 63, nl = t >> 6;
    float acc = 0.0f;
    for (int i = start + nl; i < end; i += 4) acc += h[i * 64 + c];
    red[nl][c] = acc;
    __syncthreads();
    if (t < 64) {
        float cnt = (float)(end - start);
        float inv = 1.0f / fmaxf(cnt, 1.0f);
        pooled[t] = (red[0][t] + red[1][t] + red[2][t] + red[3][t]) * inv;
    }
    __syncthreads();
    if (t < 10) {
        float s = bfv[t];
#pragma unroll
        for (int k = 0; k < 64; ++k) s = fmaf(pooled[k], Wf[k * 10 + t], s);
        hid[t] = fmaxf(s, 0.0f);
    }
    __syncthreads();
    if (t == 0) {
        float s = blv[0];
#pragma unroll
        for (int j = 0; j < 10; ++j) s = fmaf(hid[j], Wl[j], s);
        out[g] = s;
    }
}

extern "C" void kernel_launch(void* const* d_in, const int* in_sizes, int n_in,
                              void* d_out, int out_size, void* d_ws, size_t ws_size,
                              hipStream_t stream)
{
    const float* x     = (const float*)d_in[0];
    const int*   ei    = (const int*)  d_in[1];
    const int*   src   = ei;               // edge_index[0]
    const int*   dst   = ei + N_EDGES;     // edge_index[1]
    const int*   batch = (const int*)  d_in[2];
    const float* W1    = (const float*)d_in[3];
    const float* b1    = (const float*)d_in[4];
    const float* W2    = (const float*)d_in[5];
    const float* b2    = (const float*)d_in[6];
    const float* W3    = (const float*)d_in[7];
    const float* b3    = (const float*)d_in[8];
    const float* Wf    = (const float*)d_in[9];
    const float* bfv   = (const float*)d_in[10];
    const float* Wl    = (const float*)d_in[11];
    const float* blv   = (const float*)d_in[12];
    const float* eps1  = (const float*)d_in[13];
    const float* eps2  = (const float*)d_in[14];
    const float* eps3  = (const float*)d_in[15];

    // ---- workspace layout ----
    ushort16* ybf = (ushort16*)d_ws;                       // N*64 bf16 (12.8 MB)
    float* h1   = (float*)(ybf + (size_t)N_NODES * 64);    // N*64 fp32 (also h3)
    float* h2   = h1 + (size_t)N_NODES * 64;               // N*64 fp32
    int*   ints = (int*)(h2 + (size_t)N_NODES * 64);
    int*   M       = ints;                      // MTOT
    int*   Mex     = M + MTOT;                  // MTOT
    int*   Ms      = Mex + MTOT;                // MTOT (final scanned matrix)
    int*   bsum    = Ms + MTOT;                 // SCAN_NBLK (196)
    int*   row_off = bsum + 256;                // N+1
    int*   esrc    = row_off + N_NODES + 1;     // E
    uint32* tmp    = (uint32*)(esrc + N_EDGES); // E

    // ---- build CSR: two-level counting sort, LDS atomics only ----
    count_kernel<<<B1, 256, 0, stream>>>(dst, M);
    scanA_kernel<<<SCAN_NBLK, 256, 0, stream>>>(M, Mex, bsum);
    scanB_kernel<<<1, 256, 0, stream>>>(bsum);
    scanC_kernel<<<SCAN_NBLK, 256, 0, stream>>>(Mex, bsum, Ms);
    scatter_kernel<<<B1, 256, 0, stream>>>(src, dst, Ms, tmp);
    finalize_kernel<<<NB_C, 256, 0, stream>>>(tmp, Ms, row_off, esrc);

    const int gemm_blk = (N_NODES + 63) / 64;    // 1563
    const int agg_blk  = (N_NODES + 3) / 4;

    // ---- layer 1: y = x@W1 ; h1 = relu((1+e1)y + agg(y) + b1) ----
    gemm_kernel<128><<<gemm_blk, 256, 0, stream>>>(x, W1, ybf);
    aggregate_kernel<<<agg_blk, 256, 0, stream>>>((const uint32*)ybf, row_off, esrc, b1, eps1, h1);

    // ---- layer 2 ----
    gemm_kernel<64><<<gemm_blk, 256, 0, stream>>>(h1, W2, ybf);
    aggregate_kernel<<<agg_blk, 256, 0, stream>>>((const uint32*)ybf, row_off, esrc, b2, eps2, h2);

    // ---- layer 3 (reuse h1 as h3) ----
    gemm_kernel<64><<<gemm_blk, 256, 0, stream>>>(h2, W3, ybf);
    aggregate_kernel<<<agg_blk, 256, 0, stream>>>((const uint32*)ybf, row_off, esrc, b3, eps3, h1);

    // ---- pool + head ----
    pool_head_kernel<<<N_GRAPHS, 256, 0, stream>>>(h1, batch, Wf, bfv, Wl, blv,
                                                   (float*)d_out);
}